// Round 4
// baseline (333.073 us; speedup 1.0000x reference)
//
#include <hip/hip_runtime.h>

// ---------------------------------------------------------------------------
// SpatialSatCrossAttention (MS deformable attention, 6 cams, 10000 queries)
// R11: sample_k co-limited: VALU integral ~107us vs TA line floor ~94us.
//     Counter fit says v_fma_mix_f32 is half-rate (~4cyc) => 128/cam insts
//     dominate. Replace with v_pk_fma_f16 (64/cam, full rate) accumulating
//     packed f16 per camera, drained to f32 at cam end (error ~1e-3 in slots,
//     << 0.0156 absmax). Gather schedule (R10 depth-2 pipeline) unchanged.
// Launches (4):
//   1. prep_w    : weight mats -> Wt[n][k] bf16 (512 blocks)
//   2. gemm_vqk  : vproj = value @ value_W + b  (f16 out)
//                  qkcat = query @ [off|attw]_W (bf16 out)
//   3. sample_k  : deformable bilinear sampling (f16 gather, pk_fma_f16)
//                  -> slots bf16 embedded in qkcat[:,512:768]
//   4. gemm_out  : out = slots @ out_W + out_b + query (f32 d_out)
// GEMM body: 128x128 tile, 4 waves (2x2), 4x4 mfma_f32_16x16x32_bf16, BK=32,
// double-buffered LDS + register prefetch.
// ---------------------------------------------------------------------------

typedef unsigned short ushort_t;
typedef unsigned int uint_t;
typedef __attribute__((ext_vector_type(8))) short bf16x8;
typedef __attribute__((ext_vector_type(4))) float f32x4;
typedef __attribute__((ext_vector_type(2))) _Float16 f16x2;

__device__ __forceinline__ float bf2f(ushort_t u) {
    return __uint_as_float(((uint_t)u) << 16);
}
__device__ __forceinline__ ushort_t f2bf(float f) {
    uint_t i = __float_as_uint(f);
    uint_t r = i + 0x7fffu + ((i >> 16) & 1u);   // round-to-nearest-even
    return (ushort_t)(r >> 16);
}
// 8x f32 -> 8x bf16 via v_cvt_pk_bf16_f32 (RNE)
__device__ __forceinline__ bf16x8 pack8(float4 v0, float4 v1) {
    union { uint_t u[4]; bf16x8 v; } r;
    asm("v_cvt_pk_bf16_f32 %0, %1, %2" : "=v"(r.u[0]) : "v"(v0.x), "v"(v0.y));
    asm("v_cvt_pk_bf16_f32 %0, %1, %2" : "=v"(r.u[1]) : "v"(v0.z), "v"(v0.w));
    asm("v_cvt_pk_bf16_f32 %0, %1, %2" : "=v"(r.u[2]) : "v"(v1.x), "v"(v1.y));
    asm("v_cvt_pk_bf16_f32 %0, %1, %2" : "=v"(r.u[3]) : "v"(v1.z), "v"(v1.w));
    return r.v;
}
__device__ __forceinline__ ushort_t f2h(float f) {
    union { _Float16 h; ushort_t u; } cv;
    cv.h = (_Float16)f;
    return cv.u;
}

// acch[0..3] (packed f16x2, 8 channels) += wp(f16x2 dup) * f16x8(v)
__device__ __forceinline__ void pk_fma8(uint_t* a, uint_t wp, const uint4& v) {
    asm("v_pk_fma_f16 %0, %1, %2, %0" : "+v"(a[0]) : "v"(wp), "v"(v.x));
    asm("v_pk_fma_f16 %0, %1, %2, %0" : "+v"(a[1]) : "v"(wp), "v"(v.y));
    asm("v_pk_fma_f16 %0, %1, %2, %0" : "+v"(a[2]) : "v"(wp), "v"(v.z));
    asm("v_pk_fma_f16 %0, %1, %2, %0" : "+v"(a[3]) : "v"(wp), "v"(v.w));
}

// ---------------------------------------------------------------------------
// prep_w: weight transpose+convert only. W[k][N] f32 -> T[n][256] bf16.
// grid (8,16,4): z=0 value_W, z=1 out_W, z=2 off_W(512), z=3 attw_W.
// ---------------------------------------------------------------------------
__global__ __launch_bounds__(256) void prep_w(
    const float* __restrict__ Wv, const float* __restrict__ Wo,
    const float* __restrict__ Wf, const float* __restrict__ Wa,
    ushort_t* __restrict__ Tv, ushort_t* __restrict__ To,
    ushort_t* __restrict__ Tqk) {
    const int z = blockIdx.z;
    const float* W;
    ushort_t* T;
    int N;
    if (z == 0)      { W = Wv; T = Tv;              N = 256; }
    else if (z == 1) { W = Wo; T = To;              N = 256; }
    else if (z == 2) { W = Wf; T = Tqk;             N = 512; }
    else             { W = Wa; T = Tqk + 512 * 256; N = 256; }
    const int n0 = blockIdx.y * 32;
    if (n0 >= N) return;
    const int k0 = blockIdx.x * 32;

    __shared__ float tile[32][33];
    const int tx = threadIdx.x & 31;
    const int ty = threadIdx.x >> 5;   // 0..7
    #pragma unroll
    for (int r = 0; r < 4; ++r) {
        const int k = ty + r * 8;
        tile[k][tx] = W[(size_t)(k0 + k) * N + n0 + tx];
    }
    __syncthreads();
    #pragma unroll
    for (int r = 0; r < 4; ++r) {
        const int n = ty + r * 8;
        T[(size_t)(n0 + n) * 256 + k0 + tx] = f2bf(tile[tx][n]);
    }
}

// ---------------------------------------------------------------------------
// MFMA GEMM body: C[M,N] = A[M,256] @ Wt^T + bias (+resid).
// AF32: A is f32, converted to bf16 during LDS staging; else A is bf16.
// OUT_MODE: 0 = f32, 1 = bf16, 2 = f16.
// Astride: element stride between A rows (slots live embedded in qkcat).
// Wt bf16 [N][256]. N multiple of 128. 256 threads, 128x128 tile.
// ---------------------------------------------------------------------------
template <bool AF32, int OUT_MODE, bool RESID>
__device__ __forceinline__ void gemm_body(
    ushort_t (*sA)[128][32], ushort_t (*sB)[128][32],
    const void* __restrict__ Av, int Astride, const ushort_t* __restrict__ Wt,
    const float* __restrict__ bias0, const float* __restrict__ bias1, int split,
    const float* __restrict__ resid, void* __restrict__ Cv,
    int M, int N, int bx, int by) {
    const int m0 = bx * 128;
    const int n0 = by * 128;
    const int t    = threadIdx.x;
    const int lane = t & 63;
    const int w    = t >> 6;
    const int wr   = w >> 1, wc = w & 1;

    const int srow = t >> 2;          // 0..63
    const int skof = (t & 3) * 8;     // 0,8,16,24

    const bool am0 = (m0 + srow) < M;
    const bool am1 = (m0 + 64 + srow) < M;
    const float*    Af0 = (const float*)Av + (size_t)(m0 + srow) * Astride + skof;
    const float*    Af1 = Af0 + (size_t)64 * Astride;
    const ushort_t* Ab0 = (const ushort_t*)Av + (size_t)(m0 + srow) * Astride + skof;
    const ushort_t* Ab1 = Ab0 + (size_t)64 * Astride;
    const ushort_t* Bp0 = Wt + (size_t)(n0 + srow) * 256 + skof;
    const ushort_t* Bp1 = Bp0 + (size_t)64 * 256;

    const bf16x8 zz = {0, 0, 0, 0, 0, 0, 0, 0};

    auto loadA = [&](const float* af, const ushort_t* ab, int ko, bool ok) -> bf16x8 {
        if (!ok) return zz;
        if (AF32) {
            const float4 v0 = *(const float4*)(af + ko);
            const float4 v1 = *(const float4*)(af + ko + 4);
            return pack8(v0, v1);
        }
        return *(const bf16x8*)(ab + ko);
    };

    f32x4 acc[4][4];
    #pragma unroll
    for (int i = 0; i < 4; ++i)
        #pragma unroll
        for (int j = 0; j < 4; ++j)
            acc[i][j] = (f32x4){0.f, 0.f, 0.f, 0.f};

    // prologue: tile 0 -> LDS[0]
    {
        const bf16x8 a0 = loadA(Af0, Ab0, 0, am0);
        const bf16x8 a1 = loadA(Af1, Ab1, 0, am1);
        const bf16x8 b0 = *(const bf16x8*)(Bp0);
        const bf16x8 b1 = *(const bf16x8*)(Bp1);
        *(bf16x8*)(&sA[0][srow][skof])      = a0;
        *(bf16x8*)(&sA[0][64 + srow][skof]) = a1;
        *(bf16x8*)(&sB[0][srow][skof])      = b0;
        *(bf16x8*)(&sB[0][64 + srow][skof]) = b1;
    }
    __syncthreads();

    const int rl = lane & 15;
    const int kq = (lane >> 4) * 8;

    for (int k = 0; k < 8; ++k) {
        const int buf = k & 1;

        bf16x8 na0 = zz, na1 = zz, nb0 = zz, nb1 = zz;
        if (k < 7) {
            const int ko = (k + 1) * 32;
            na0 = loadA(Af0, Ab0, ko, am0);
            na1 = loadA(Af1, Ab1, ko, am1);
            nb0 = *(const bf16x8*)(Bp0 + ko);
            nb1 = *(const bf16x8*)(Bp1 + ko);
        }

        bf16x8 af[4], bfr[4];
        #pragma unroll
        for (int i = 0; i < 4; ++i)
            af[i] = *(const bf16x8*)(&sA[buf][wr * 64 + i * 16 + rl][kq]);
        #pragma unroll
        for (int j = 0; j < 4; ++j)
            bfr[j] = *(const bf16x8*)(&sB[buf][wc * 64 + j * 16 + rl][kq]);
        #pragma unroll
        for (int i = 0; i < 4; ++i)
            #pragma unroll
            for (int j = 0; j < 4; ++j)
                acc[i][j] = __builtin_amdgcn_mfma_f32_16x16x32_bf16(
                    af[i], bfr[j], acc[i][j], 0, 0, 0);

        if (k < 7) {
            __syncthreads();
            *(bf16x8*)(&sA[buf ^ 1][srow][skof])      = na0;
            *(bf16x8*)(&sA[buf ^ 1][64 + srow][skof]) = na1;
            *(bf16x8*)(&sB[buf ^ 1][srow][skof])      = nb0;
            *(bf16x8*)(&sB[buf ^ 1][64 + srow][skof]) = nb1;
            __syncthreads();
        }
    }

    // --- epilogue: C/D layout col=lane&15, row=(lane>>4)*4+reg (m89) ---
    const int col_l = lane & 15;
    const int rq    = (lane >> 4) * 4;
    #pragma unroll
    for (int j = 0; j < 4; ++j) {
        const int gn = n0 + wc * 64 + j * 16 + col_l;
        const float bj = (gn < split) ? bias0[gn] : bias1[gn - split];
        #pragma unroll
        for (int i = 0; i < 4; ++i) {
            #pragma unroll
            for (int r = 0; r < 4; ++r) {
                const int gm = m0 + wr * 64 + i * 16 + rq + r;
                if (gm >= M) continue;
                float v = acc[i][j][r] + bj;
                if (RESID) v += resid[(size_t)gm * N + gn];
                if (OUT_MODE == 1)
                    ((ushort_t*)Cv)[(size_t)gm * N + gn] = f2bf(v);
                else if (OUT_MODE == 2)
                    ((ushort_t*)Cv)[(size_t)gm * N + gn] = f2h(v);
                else
                    ((float*)Cv)[(size_t)gm * N + gn] = v;
            }
        }
    }
}

// Fused independent GEMMs: blocks [0,510) -> vproj (f16 out),
//                          [510,984) -> qkcat (bf16 out).
__global__ __launch_bounds__(256) void gemm_vqk(
    const float* __restrict__ value, const ushort_t* __restrict__ value_Wt,
    const float* __restrict__ value_b, ushort_t* __restrict__ vproj,
    const float* __restrict__ query, const ushort_t* __restrict__ qk_Wt,
    const float* __restrict__ off_b, const float* __restrict__ attw_b,
    ushort_t* __restrict__ qkcat) {
    __shared__ ushort_t sA[2][128][32];
    __shared__ ushort_t sB[2][128][32];
    int b = blockIdx.x;
    if (b < 510) {
        gemm_body<true, 2, false>(sA, sB, value, 256, value_Wt, value_b,
                                  value_b, 256, nullptr, (void*)vproj,
                                  32640, 256, b % 255, b / 255);
    } else {
        b -= 510;
        gemm_body<true, 1, false>(sA, sB, query, 256, qk_Wt, off_b, attw_b,
                                  512, nullptr, (void*)qkcat, 10000, 768,
                                  b % 79, b / 79);
    }
}

__global__ __launch_bounds__(256) void gemm_out_k(
    const ushort_t* __restrict__ slots,   // = qkcat + 512, row stride 768
    const ushort_t* __restrict__ out_Wt,
    const float* __restrict__ out_b, const float* __restrict__ query,
    float* __restrict__ out) {
    __shared__ ushort_t sA[2][128][32];
    __shared__ ushort_t sB[2][128][32];
    gemm_body<false, 0, true>(sA, sB, slots, 768, out_Wt, out_b, out_b, 256,
                              query, (void*)out, 10000, 256,
                              blockIdx.x, blockIdx.y);
}

// ---------------------------------------------------------------------------
// Deformable sampling. 1 block per query, 256 threads.
//   setup role : (h, lp = tid&31)  -> corner byte-offset/weight for (h,lvl,p)
//   gather role: (h, slice, g)     -> 16B f16 loads, v_pk_fma_f16 accumulate
// R10 gather schedule (per-j groups, depth-2 pipeline). Weights shuffled as
// packed-f16 duplicates; per-camera packed accumulation drained to f32.
// Slot row written back into qkcat[:,512:768) as bf16.
// ---------------------------------------------------------------------------
__global__ __launch_bounds__(256) void sample_k(
    ushort_t* __restrict__ qkcat,        // bf16 [10000, 768]
    const float* __restrict__ refp,      // f32 [6,1,10000,4,2]
    const int* __restrict__ vox,         // int32 [6,1,10000,4]
    const ushort_t* __restrict__ vproj) {// f16 [6*5440, 256]
    const int q   = blockIdx.x;
    const int tid = threadIdx.x;
    const int lane  = tid & 63;
    const int h     = tid >> 5;
    const int lp    = tid & 31;          // setup role
    const int slice = (tid >> 2) & 7;    // gather role
    const int g     = tid & 3;           // gather role: channels g*8..g*8+7

    __shared__ float s_valid[8];
    __shared__ float s_red[256][8];      // [tid][chan-in-group]

    if (tid < 6) {
        const int base = (tid * 10000 + q) * 4;
        const int mm = vox[base] | vox[base + 1] | vox[base + 2] | vox[base + 3];
        s_valid[tid] = mm ? 1.0f : 0.0f;
    }

    // ---- softmax over 32 (lvl,p) entries within each head ----
    const float a = bf2f(qkcat[(size_t)q * 768 + 512 + tid]);
    float mx = a;
    #pragma unroll
    for (int o = 16; o >= 1; o >>= 1) mx = fmaxf(mx, __shfl_xor(mx, o));
    const float e = __expf(a - mx);
    float se = e;
    #pragma unroll
    for (int o = 16; o >= 1; o >>= 1) se += __shfl_xor(se, o);
    const float aw = e / se;

    // ---- camera-independent part of this thread's sample location ----
    const int lvl = lp >> 3;
    const int p   = lp & 7;
    const int dd  = p & 3;
    const int   Sarr[4]   = {64, 32, 16, 8};
    const int   Lstart[4] = {0, 4096, 5120, 5376};
    const int   S  = Sarr[lvl];
    const float Sf = (float)S;
    const int   lstart = Lstart[lvl];
    const int   hoff   = h << 6;     // head byte offset within a row (32ch*2B)
    const float ox = bf2f(qkcat[(size_t)q * 768 + h * 64 + lvl * 16 + p * 2 + 0]) / Sf;
    const float oy = bf2f(qkcat[(size_t)q * 768 + h * 64 + lvl * 16 + p * 2 + 1]) / Sf;

    __syncthreads();
    float sv[6];
    #pragma unroll
    for (int c = 0; c < 6; ++c) sv[c] = s_valid[c];
    const float cnt = sv[0] + sv[1] + sv[2] + sv[3] + sv[4] + sv[5];

    float acc[8] = {0.f, 0.f, 0.f, 0.f, 0.f, 0.f, 0.f, 0.f};
    const char* vpb = (const char*)vproj;
    const int goff = g << 4;             // 4 lanes x 16B within 64B chunk
    const int srcbase = (lane & 32) + slice * 4;

    for (int c = 0; c < 6; ++c) {
        if (sv[c] == 0.0f) continue;     // block-uniform branch

        // ---- setup: corner BYTE offsets + packed-f16 weights ----
        int    cb[4];
        uint_t cwp[4];
        {
            const int cbase = c * 5440 + lstart;
            const int rbase = ((c * 10000 + q) * 4 + dd) * 2;
            const float rx = refp[rbase + 0];
            const float ry = refp[rbase + 1];
            const float x  = (rx + ox) * Sf - 0.5f;
            const float y  = (ry + oy) * Sf - 0.5f;
            const float x0 = floorf(x), y0 = floorf(y);
            #pragma unroll
            for (int k = 0; k < 4; ++k) {
                const float cx = x0 + (float)(k & 1);
                const float cy = y0 + (float)(k >> 1);
                const float wgt = (1.0f - fabsf(x - cx)) * (1.0f - fabsf(y - cy));
                const bool ok = (cx >= 0.0f) & (cx < Sf) & (cy >= 0.0f) & (cy < Sf);
                const int xi = (int)fminf(fmaxf(cx, 0.0f), Sf - 1.0f);
                const int yi = (int)fminf(fmaxf(cy, 0.0f), Sf - 1.0f);
                cb[k] = ((cbase + yi * S + xi) << 9) + hoff;   // bytes
                const float cw = ok ? wgt * aw : 0.0f;
                const uint_t hw = (uint_t)f2h(cw);
                cwp[k] = (hw << 16) | hw;                      // f16 dup
            }
        }

        // ---- exchange byte offsets for all 4 groups ----
        int b[4][4];
        #pragma unroll
        for (int j = 0; j < 4; ++j) {
            const int src = srcbase + j;
            b[j][0] = __shfl(cb[0], src);
            b[j][1] = __shfl(cb[1], src);
            b[j][2] = __shfl(cb[2], src);
            b[j][3] = __shfl(cb[3], src);
        }

        // ---- depth-2 pipelined gather: group j+1 in flight during j ----
        uint_t acch[4] = {0u, 0u, 0u, 0u};   // packed f16x2, 8 channels
        uint4 v0 = *(const uint4*)(vpb + (b[0][0] + goff));
        uint4 v1 = *(const uint4*)(vpb + (b[0][1] + goff));
        uint4 v2 = *(const uint4*)(vpb + (b[0][2] + goff));
        uint4 v3 = *(const uint4*)(vpb + (b[0][3] + goff));
        #pragma unroll
        for (int j = 0; j < 4; ++j) {
            uint4 n0 = v0, n1 = v1, n2 = v2, n3 = v3;
            if (j < 3) {
                n0 = *(const uint4*)(vpb + (b[j + 1][0] + goff));
                n1 = *(const uint4*)(vpb + (b[j + 1][1] + goff));
                n2 = *(const uint4*)(vpb + (b[j + 1][2] + goff));
                n3 = *(const uint4*)(vpb + (b[j + 1][3] + goff));
            }
            const int src = srcbase + j;
            const uint_t w0 = (uint_t)__shfl((int)cwp[0], src);
            const uint_t w1 = (uint_t)__shfl((int)cwp[1], src);
            const uint_t w2 = (uint_t)__shfl((int)cwp[2], src);
            const uint_t w3 = (uint_t)__shfl((int)cwp[3], src);
            pk_fma8(acch, w0, v0);
            pk_fma8(acch, w1, v1);
            pk_fma8(acch, w2, v2);
            pk_fma8(acch, w3, v3);
            v0 = n0; v1 = n1; v2 = n2; v3 = n3;
        }

        // ---- drain packed f16 accumulators to f32 (once per camera) ----
        #pragma unroll
        for (int n = 0; n < 4; ++n) {
            union { uint_t u; f16x2 h; } cvu;
            cvu.u = acch[n];
            acc[2 * n]     += (float)cvu.h.x;
            acc[2 * n + 1] += (float)cvu.h.y;
        }
    }

    // ---- cross-slice reduction ----
    #pragma unroll
    for (int n = 0; n < 8; ++n) s_red[tid][n] = acc[n];
    __syncthreads();

    const int cch = tid & 31;
    float sum = 0.0f;
    #pragma unroll
    for (int s = 0; s < 8; ++s)
        sum += s_red[h * 32 + s * 4 + (cch >> 3)][cch & 7];

    // slot row overwrites this query's attw logits (all read above)
    qkcat[(size_t)q * 768 + 512 + tid] = f2bf(sum / fmaxf(cnt, 1.0f));
}

// ---------------------------------------------------------------------------
extern "C" void kernel_launch(void* const* d_in, const int* in_sizes, int n_in,
                              void* d_out, int out_size, void* d_ws, size_t ws_size,
                              hipStream_t stream) {
    const float* query   = (const float*)d_in[0];
    // d_in[1] = key : unused by the deformable-attention math
    const float* value   = (const float*)d_in[2];   // (6,5440,1,256) -> (32640,256)
    const float* refp    = (const float*)d_in[3];
    const int*   vox     = (const int*)d_in[4];
    // d_in[5] spatial_shapes, d_in[6] level_start_index : compile-time constants
    const float* value_W = (const float*)d_in[7];
    const float* value_b = (const float*)d_in[8];
    const float* off_W   = (const float*)d_in[9];
    const float* off_b   = (const float*)d_in[10];
    const float* attw_W  = (const float*)d_in[11];
    const float* attw_b  = (const float*)d_in[12];
    const float* out_W   = (const float*)d_in[13];
    const float* out_b   = (const float*)d_in[14];
    float* out = (float*)d_out;

    // ws layout (bytes):
    //   [0,        16711680)  vproj f16 [32640][256]
    //   [16711680, 32071680)  qkcat bf16 [10000][768] (slots in cols 512..768)
    //   [32071680, 32727040)  value_Wt | out_Wt | qk_Wt  bf16
    char* ws = (char*)d_ws;
    ushort_t* vproj    = (ushort_t*)ws;
    ushort_t* qkcat    = (ushort_t*)(ws + 16711680);
    ushort_t* value_Wt = (ushort_t*)(ws + 32071680);
    ushort_t* out_Wt   = (ushort_t*)(ws + 32071680 + 131072);
    ushort_t* qk_Wt    = (ushort_t*)(ws + 32071680 + 262144);

    // 1. weight transpose+convert -> Wt[n][k] bf16
    prep_w<<<dim3(8, 16, 4), 256, 0, stream>>>(
        value_W, out_W, off_W, attw_W, value_Wt, out_Wt, qk_Wt);
    // 2. fused value-proj (f16 out) + offset/attw-proj (bf16 out)
    gemm_vqk<<<984, 256, 0, stream>>>(value, value_Wt, value_b, vproj,
                                      query, qk_Wt, off_b, attw_b, qkcat);
    // 3. deformable sampling + softmax + camera mask/count -> slots in qkcat
    sample_k<<<10000, 256, 0, stream>>>(qkcat, refp, vox, vproj);
    // 4. output projection + residual, f32 out
    gemm_out_k<<<dim3(79, 2), 256, 0, stream>>>(qkcat + 512, out_Wt, out_b,
                                                query, out);
}

// Round 5
// 325.753 us; speedup vs baseline: 1.0225x; 1.0225x over previous
//
#include <hip/hip_runtime.h>

// ---------------------------------------------------------------------------
// SpatialSatCrossAttention (MS deformable attention, 6 cams, 10000 queries)
// R12: sample_k co-limited (VALU ~93us, TA floor ~94us, achieved 150us) =>
//     overlap/occupancy problem, not pipe throughput. Heads are independent:
//     restructure to 128-thread blocks (4 heads), grid (10000,2): ZERO
//     barriers, ZERO LDS (slice reduction via shfl_xor tree over slice bits
//     4/8/16; validity via lane loads + shuffles; slots packed to one 16B
//     store per writer lane). R11 gather inner loop unchanged.
// Launches (4):
//   1. prep_w    : weight mats -> Wt[n][k] bf16 (512 blocks)
//   2. gemm_vqk  : vproj = value @ value_W + b  (f16 out)
//                  qkcat = query @ [off|attw]_W (bf16 out)
//   3. sample_k  : deformable bilinear sampling (f16 gather, pk_fma_f16)
//                  -> slots bf16 embedded in qkcat[:,512:768]
//   4. gemm_out  : out = slots @ out_W + out_b + query (f32 d_out)
// GEMM body: 128x128 tile, 4 waves (2x2), 4x4 mfma_f32_16x16x32_bf16, BK=32,
// double-buffered LDS + register prefetch.
// ---------------------------------------------------------------------------

typedef unsigned short ushort_t;
typedef unsigned int uint_t;
typedef __attribute__((ext_vector_type(8))) short bf16x8;
typedef __attribute__((ext_vector_type(4))) float f32x4;
typedef __attribute__((ext_vector_type(2))) _Float16 f16x2;

__device__ __forceinline__ float bf2f(ushort_t u) {
    return __uint_as_float(((uint_t)u) << 16);
}
__device__ __forceinline__ ushort_t f2bf(float f) {
    uint_t i = __float_as_uint(f);
    uint_t r = i + 0x7fffu + ((i >> 16) & 1u);   // round-to-nearest-even
    return (ushort_t)(r >> 16);
}
// 8x f32 -> 8x bf16 via v_cvt_pk_bf16_f32 (RNE)
__device__ __forceinline__ bf16x8 pack8(float4 v0, float4 v1) {
    union { uint_t u[4]; bf16x8 v; } r;
    asm("v_cvt_pk_bf16_f32 %0, %1, %2" : "=v"(r.u[0]) : "v"(v0.x), "v"(v0.y));
    asm("v_cvt_pk_bf16_f32 %0, %1, %2" : "=v"(r.u[1]) : "v"(v0.z), "v"(v0.w));
    asm("v_cvt_pk_bf16_f32 %0, %1, %2" : "=v"(r.u[2]) : "v"(v1.x), "v"(v1.y));
    asm("v_cvt_pk_bf16_f32 %0, %1, %2" : "=v"(r.u[3]) : "v"(v1.z), "v"(v1.w));
    return r.v;
}
__device__ __forceinline__ ushort_t f2h(float f) {
    union { _Float16 h; ushort_t u; } cv;
    cv.h = (_Float16)f;
    return cv.u;
}

// acch[0..3] (packed f16x2, 8 channels) += wp(f16x2 dup) * f16x8(v)
__device__ __forceinline__ void pk_fma8(uint_t* a, uint_t wp, const uint4& v) {
    asm("v_pk_fma_f16 %0, %1, %2, %0" : "+v"(a[0]) : "v"(wp), "v"(v.x));
    asm("v_pk_fma_f16 %0, %1, %2, %0" : "+v"(a[1]) : "v"(wp), "v"(v.y));
    asm("v_pk_fma_f16 %0, %1, %2, %0" : "+v"(a[2]) : "v"(wp), "v"(v.z));
    asm("v_pk_fma_f16 %0, %1, %2, %0" : "+v"(a[3]) : "v"(wp), "v"(v.w));
}

// ---------------------------------------------------------------------------
// prep_w: weight transpose+convert only. W[k][N] f32 -> T[n][256] bf16.
// grid (8,16,4): z=0 value_W, z=1 out_W, z=2 off_W(512), z=3 attw_W.
// ---------------------------------------------------------------------------
__global__ __launch_bounds__(256) void prep_w(
    const float* __restrict__ Wv, const float* __restrict__ Wo,
    const float* __restrict__ Wf, const float* __restrict__ Wa,
    ushort_t* __restrict__ Tv, ushort_t* __restrict__ To,
    ushort_t* __restrict__ Tqk) {
    const int z = blockIdx.z;
    const float* W;
    ushort_t* T;
    int N;
    if (z == 0)      { W = Wv; T = Tv;              N = 256; }
    else if (z == 1) { W = Wo; T = To;              N = 256; }
    else if (z == 2) { W = Wf; T = Tqk;             N = 512; }
    else             { W = Wa; T = Tqk + 512 * 256; N = 256; }
    const int n0 = blockIdx.y * 32;
    if (n0 >= N) return;
    const int k0 = blockIdx.x * 32;

    __shared__ float tile[32][33];
    const int tx = threadIdx.x & 31;
    const int ty = threadIdx.x >> 5;   // 0..7
    #pragma unroll
    for (int r = 0; r < 4; ++r) {
        const int k = ty + r * 8;
        tile[k][tx] = W[(size_t)(k0 + k) * N + n0 + tx];
    }
    __syncthreads();
    #pragma unroll
    for (int r = 0; r < 4; ++r) {
        const int n = ty + r * 8;
        T[(size_t)(n0 + n) * 256 + k0 + tx] = f2bf(tile[tx][n]);
    }
}

// ---------------------------------------------------------------------------
// MFMA GEMM body: C[M,N] = A[M,256] @ Wt^T + bias (+resid).
// AF32: A is f32, converted to bf16 during LDS staging; else A is bf16.
// OUT_MODE: 0 = f32, 1 = bf16, 2 = f16.
// Astride: element stride between A rows (slots live embedded in qkcat).
// Wt bf16 [N][256]. N multiple of 128. 256 threads, 128x128 tile.
// ---------------------------------------------------------------------------
template <bool AF32, int OUT_MODE, bool RESID>
__device__ __forceinline__ void gemm_body(
    ushort_t (*sA)[128][32], ushort_t (*sB)[128][32],
    const void* __restrict__ Av, int Astride, const ushort_t* __restrict__ Wt,
    const float* __restrict__ bias0, const float* __restrict__ bias1, int split,
    const float* __restrict__ resid, void* __restrict__ Cv,
    int M, int N, int bx, int by) {
    const int m0 = bx * 128;
    const int n0 = by * 128;
    const int t    = threadIdx.x;
    const int lane = t & 63;
    const int w    = t >> 6;
    const int wr   = w >> 1, wc = w & 1;

    const int srow = t >> 2;          // 0..63
    const int skof = (t & 3) * 8;     // 0,8,16,24

    const bool am0 = (m0 + srow) < M;
    const bool am1 = (m0 + 64 + srow) < M;
    const float*    Af0 = (const float*)Av + (size_t)(m0 + srow) * Astride + skof;
    const float*    Af1 = Af0 + (size_t)64 * Astride;
    const ushort_t* Ab0 = (const ushort_t*)Av + (size_t)(m0 + srow) * Astride + skof;
    const ushort_t* Ab1 = Ab0 + (size_t)64 * Astride;
    const ushort_t* Bp0 = Wt + (size_t)(n0 + srow) * 256 + skof;
    const ushort_t* Bp1 = Bp0 + (size_t)64 * 256;

    const bf16x8 zz = {0, 0, 0, 0, 0, 0, 0, 0};

    auto loadA = [&](const float* af, const ushort_t* ab, int ko, bool ok) -> bf16x8 {
        if (!ok) return zz;
        if (AF32) {
            const float4 v0 = *(const float4*)(af + ko);
            const float4 v1 = *(const float4*)(af + ko + 4);
            return pack8(v0, v1);
        }
        return *(const bf16x8*)(ab + ko);
    };

    f32x4 acc[4][4];
    #pragma unroll
    for (int i = 0; i < 4; ++i)
        #pragma unroll
        for (int j = 0; j < 4; ++j)
            acc[i][j] = (f32x4){0.f, 0.f, 0.f, 0.f};

    // prologue: tile 0 -> LDS[0]
    {
        const bf16x8 a0 = loadA(Af0, Ab0, 0, am0);
        const bf16x8 a1 = loadA(Af1, Ab1, 0, am1);
        const bf16x8 b0 = *(const bf16x8*)(Bp0);
        const bf16x8 b1 = *(const bf16x8*)(Bp1);
        *(bf16x8*)(&sA[0][srow][skof])      = a0;
        *(bf16x8*)(&sA[0][64 + srow][skof]) = a1;
        *(bf16x8*)(&sB[0][srow][skof])      = b0;
        *(bf16x8*)(&sB[0][64 + srow][skof]) = b1;
    }
    __syncthreads();

    const int rl = lane & 15;
    const int kq = (lane >> 4) * 8;

    for (int k = 0; k < 8; ++k) {
        const int buf = k & 1;

        bf16x8 na0 = zz, na1 = zz, nb0 = zz, nb1 = zz;
        if (k < 7) {
            const int ko = (k + 1) * 32;
            na0 = loadA(Af0, Ab0, ko, am0);
            na1 = loadA(Af1, Ab1, ko, am1);
            nb0 = *(const bf16x8*)(Bp0 + ko);
            nb1 = *(const bf16x8*)(Bp1 + ko);
        }

        bf16x8 af[4], bfr[4];
        #pragma unroll
        for (int i = 0; i < 4; ++i)
            af[i] = *(const bf16x8*)(&sA[buf][wr * 64 + i * 16 + rl][kq]);
        #pragma unroll
        for (int j = 0; j < 4; ++j)
            bfr[j] = *(const bf16x8*)(&sB[buf][wc * 64 + j * 16 + rl][kq]);
        #pragma unroll
        for (int i = 0; i < 4; ++i)
            #pragma unroll
            for (int j = 0; j < 4; ++j)
                acc[i][j] = __builtin_amdgcn_mfma_f32_16x16x32_bf16(
                    af[i], bfr[j], acc[i][j], 0, 0, 0);

        if (k < 7) {
            __syncthreads();
            *(bf16x8*)(&sA[buf ^ 1][srow][skof])      = na0;
            *(bf16x8*)(&sA[buf ^ 1][64 + srow][skof]) = na1;
            *(bf16x8*)(&sB[buf ^ 1][srow][skof])      = nb0;
            *(bf16x8*)(&sB[buf ^ 1][64 + srow][skof]) = nb1;
            __syncthreads();
        }
    }

    // --- epilogue: C/D layout col=lane&15, row=(lane>>4)*4+reg (m89) ---
    const int col_l = lane & 15;
    const int rq    = (lane >> 4) * 4;
    #pragma unroll
    for (int j = 0; j < 4; ++j) {
        const int gn = n0 + wc * 64 + j * 16 + col_l;
        const float bj = (gn < split) ? bias0[gn] : bias1[gn - split];
        #pragma unroll
        for (int i = 0; i < 4; ++i) {
            #pragma unroll
            for (int r = 0; r < 4; ++r) {
                const int gm = m0 + wr * 64 + i * 16 + rq + r;
                if (gm >= M) continue;
                float v = acc[i][j][r] + bj;
                if (RESID) v += resid[(size_t)gm * N + gn];
                if (OUT_MODE == 1)
                    ((ushort_t*)Cv)[(size_t)gm * N + gn] = f2bf(v);
                else if (OUT_MODE == 2)
                    ((ushort_t*)Cv)[(size_t)gm * N + gn] = f2h(v);
                else
                    ((float*)Cv)[(size_t)gm * N + gn] = v;
            }
        }
    }
}

// Fused independent GEMMs: blocks [0,510) -> vproj (f16 out),
//                          [510,984) -> qkcat (bf16 out).
__global__ __launch_bounds__(256) void gemm_vqk(
    const float* __restrict__ value, const ushort_t* __restrict__ value_Wt,
    const float* __restrict__ value_b, ushort_t* __restrict__ vproj,
    const float* __restrict__ query, const ushort_t* __restrict__ qk_Wt,
    const float* __restrict__ off_b, const float* __restrict__ attw_b,
    ushort_t* __restrict__ qkcat) {
    __shared__ ushort_t sA[2][128][32];
    __shared__ ushort_t sB[2][128][32];
    int b = blockIdx.x;
    if (b < 510) {
        gemm_body<true, 2, false>(sA, sB, value, 256, value_Wt, value_b,
                                  value_b, 256, nullptr, (void*)vproj,
                                  32640, 256, b % 255, b / 255);
    } else {
        b -= 510;
        gemm_body<true, 1, false>(sA, sB, query, 256, qk_Wt, off_b, attw_b,
                                  512, nullptr, (void*)qkcat, 10000, 768,
                                  b % 79, b / 79);
    }
}

__global__ __launch_bounds__(256) void gemm_out_k(
    const ushort_t* __restrict__ slots,   // = qkcat + 512, row stride 768
    const ushort_t* __restrict__ out_Wt,
    const float* __restrict__ out_b, const float* __restrict__ query,
    float* __restrict__ out) {
    __shared__ ushort_t sA[2][128][32];
    __shared__ ushort_t sB[2][128][32];
    gemm_body<false, 0, true>(sA, sB, slots, 768, out_Wt, out_b, out_b, 256,
                              query, (void*)out, 10000, 256,
                              blockIdx.x, blockIdx.y);
}

// ---------------------------------------------------------------------------
// Deformable sampling. grid (10000, 2), 128 threads (4 heads per block).
// Barrier-free, LDS-free: heads are independent; a head's 8 slices live in
// one 64-lane wave, so the cross-slice reduction is a shfl_xor tree over the
// slice bits (4/8/16). Validity masks via 6 lane loads + wave shuffles.
// Slot row (8 channels per writer lane) packed via v_cvt_pk_bf16_f32 into
// one 16B store. Gather/compute inner loop identical to R11.
// ---------------------------------------------------------------------------
__global__ __launch_bounds__(128) void sample_k(
    ushort_t* __restrict__ qkcat,        // bf16 [10000, 768]
    const float* __restrict__ refp,      // f32 [6,1,10000,4,2]
    const int* __restrict__ vox,         // int32 [6,1,10000,4]
    const ushort_t* __restrict__ vproj) {// f16 [6*5440, 256]
    const int q    = blockIdx.x;
    const int hb   = blockIdx.y << 2;    // head base: 0 or 4
    const int tid  = threadIdx.x;        // 0..127
    const int lane = tid & 63;
    const int h    = hb + (tid >> 5);    // this thread's head
    const int lp   = tid & 31;           // setup role: (lvl,p)
    const int slice = (tid >> 2) & 7;    // gather role
    const int g     = tid & 3;           // gather role: channels g*8..g*8+7

    // ---- validity: lanes 0..5 load their cam's vox row, broadcast ----
    int mm = 0;
    if (lane < 6) {
        const uint4 vm = *(const uint4*)(vox + ((lane * 10000 + q) << 2));
        mm = (int)(vm.x | vm.y | vm.z | vm.w);
    }
    float sv[6];
    #pragma unroll
    for (int c = 0; c < 6; ++c) sv[c] = __shfl(mm, c) ? 1.0f : 0.0f;
    const float cnt = sv[0] + sv[1] + sv[2] + sv[3] + sv[4] + sv[5];

    // ---- softmax over 32 (lvl,p) entries within this head ----
    const float a = bf2f(qkcat[(size_t)q * 768 + 512 + h * 32 + lp]);
    float mx = a;
    #pragma unroll
    for (int o = 16; o >= 1; o >>= 1) mx = fmaxf(mx, __shfl_xor(mx, o));
    const float e = __expf(a - mx);
    float se = e;
    #pragma unroll
    for (int o = 16; o >= 1; o >>= 1) se += __shfl_xor(se, o);
    const float aw = e / se;

    // ---- camera-independent part of this thread's sample location ----
    const int lvl = lp >> 3;
    const int p   = lp & 7;
    const int dd  = p & 3;
    const int   Sarr[4]   = {64, 32, 16, 8};
    const int   Lstart[4] = {0, 4096, 5120, 5376};
    const int   S  = Sarr[lvl];
    const float Sf = (float)S;
    const int   lstart = Lstart[lvl];
    const int   hoff   = h << 6;     // head byte offset within a row (32ch*2B)
    const float ox = bf2f(qkcat[(size_t)q * 768 + h * 64 + lvl * 16 + p * 2 + 0]) / Sf;
    const float oy = bf2f(qkcat[(size_t)q * 768 + h * 64 + lvl * 16 + p * 2 + 1]) / Sf;

    float acc[8] = {0.f, 0.f, 0.f, 0.f, 0.f, 0.f, 0.f, 0.f};
    const char* vpb = (const char*)vproj;
    const int goff = g << 4;             // 4 lanes x 16B within 64B chunk
    const int srcbase = (lane & 32) + slice * 4;

    for (int c = 0; c < 6; ++c) {
        if (sv[c] == 0.0f) continue;     // block-uniform branch

        // ---- setup: corner BYTE offsets + packed-f16 weights ----
        int    cb[4];
        uint_t cwp[4];
        {
            const int cbase = c * 5440 + lstart;
            const int rbase = ((c * 10000 + q) * 4 + dd) * 2;
            const float rx = refp[rbase + 0];
            const float ry = refp[rbase + 1];
            const float x  = (rx + ox) * Sf - 0.5f;
            const float y  = (ry + oy) * Sf - 0.5f;
            const float x0 = floorf(x), y0 = floorf(y);
            #pragma unroll
            for (int k = 0; k < 4; ++k) {
                const float cx = x0 + (float)(k & 1);
                const float cy = y0 + (float)(k >> 1);
                const float wgt = (1.0f - fabsf(x - cx)) * (1.0f - fabsf(y - cy));
                const bool ok = (cx >= 0.0f) & (cx < Sf) & (cy >= 0.0f) & (cy < Sf);
                const int xi = (int)fminf(fmaxf(cx, 0.0f), Sf - 1.0f);
                const int yi = (int)fminf(fmaxf(cy, 0.0f), Sf - 1.0f);
                cb[k] = ((cbase + yi * S + xi) << 9) + hoff;   // bytes
                const float cw = ok ? wgt * aw : 0.0f;
                const uint_t hw = (uint_t)f2h(cw);
                cwp[k] = (hw << 16) | hw;                      // f16 dup
            }
        }

        // ---- exchange byte offsets for all 4 groups ----
        int b[4][4];
        #pragma unroll
        for (int j = 0; j < 4; ++j) {
            const int src = srcbase + j;
            b[j][0] = __shfl(cb[0], src);
            b[j][1] = __shfl(cb[1], src);
            b[j][2] = __shfl(cb[2], src);
            b[j][3] = __shfl(cb[3], src);
        }

        // ---- depth-2 pipelined gather: group j+1 in flight during j ----
        uint_t acch[4] = {0u, 0u, 0u, 0u};   // packed f16x2, 8 channels
        uint4 v0 = *(const uint4*)(vpb + (b[0][0] + goff));
        uint4 v1 = *(const uint4*)(vpb + (b[0][1] + goff));
        uint4 v2 = *(const uint4*)(vpb + (b[0][2] + goff));
        uint4 v3 = *(const uint4*)(vpb + (b[0][3] + goff));
        #pragma unroll
        for (int j = 0; j < 4; ++j) {
            uint4 n0 = v0, n1 = v1, n2 = v2, n3 = v3;
            if (j < 3) {
                n0 = *(const uint4*)(vpb + (b[j + 1][0] + goff));
                n1 = *(const uint4*)(vpb + (b[j + 1][1] + goff));
                n2 = *(const uint4*)(vpb + (b[j + 1][2] + goff));
                n3 = *(const uint4*)(vpb + (b[j + 1][3] + goff));
            }
            const int src = srcbase + j;
            const uint_t w0 = (uint_t)__shfl((int)cwp[0], src);
            const uint_t w1 = (uint_t)__shfl((int)cwp[1], src);
            const uint_t w2 = (uint_t)__shfl((int)cwp[2], src);
            const uint_t w3 = (uint_t)__shfl((int)cwp[3], src);
            pk_fma8(acch, w0, v0);
            pk_fma8(acch, w1, v1);
            pk_fma8(acch, w2, v2);
            pk_fma8(acch, w3, v3);
            v0 = n0; v1 = n1; v2 = n2; v3 = n3;
        }

        // ---- drain packed f16 accumulators to f32 (once per camera) ----
        #pragma unroll
        for (int n = 0; n < 4; ++n) {
            union { uint_t u; f16x2 h; } cvu;
            cvu.u = acch[n];
            acc[2 * n]     += (float)cvu.h.x;
            acc[2 * n + 1] += (float)cvu.h.y;
        }
    }

    // ---- cross-slice reduction: shfl_xor tree over slice bits (4/8/16) ----
    #pragma unroll
    for (int n = 0; n < 8; ++n) {
        acc[n] += __shfl_xor(acc[n], 4);
        acc[n] += __shfl_xor(acc[n], 8);
        acc[n] += __shfl_xor(acc[n], 16);
    }

    // ---- slot write: slice==0 lanes pack 8 channels -> one 16B store ----
    if (slice == 0) {
        const float inv = 1.0f / fmaxf(cnt, 1.0f);
        uint4 r;
        asm("v_cvt_pk_bf16_f32 %0, %1, %2"
            : "=v"(r.x) : "v"(acc[0] * inv), "v"(acc[1] * inv));
        asm("v_cvt_pk_bf16_f32 %0, %1, %2"
            : "=v"(r.y) : "v"(acc[2] * inv), "v"(acc[3] * inv));
        asm("v_cvt_pk_bf16_f32 %0, %1, %2"
            : "=v"(r.z) : "v"(acc[4] * inv), "v"(acc[5] * inv));
        asm("v_cvt_pk_bf16_f32 %0, %1, %2"
            : "=v"(r.w) : "v"(acc[6] * inv), "v"(acc[7] * inv));
        *(uint4*)(&qkcat[(size_t)q * 768 + 512 + h * 32 + g * 8]) = r;
    }
}

// ---------------------------------------------------------------------------
extern "C" void kernel_launch(void* const* d_in, const int* in_sizes, int n_in,
                              void* d_out, int out_size, void* d_ws, size_t ws_size,
                              hipStream_t stream) {
    const float* query   = (const float*)d_in[0];
    // d_in[1] = key : unused by the deformable-attention math
    const float* value   = (const float*)d_in[2];   // (6,5440,1,256) -> (32640,256)
    const float* refp    = (const float*)d_in[3];
    const int*   vox     = (const int*)d_in[4];
    // d_in[5] spatial_shapes, d_in[6] level_start_index : compile-time constants
    const float* value_W = (const float*)d_in[7];
    const float* value_b = (const float*)d_in[8];
    const float* off_W   = (const float*)d_in[9];
    const float* off_b   = (const float*)d_in[10];
    const float* attw_W  = (const float*)d_in[11];
    const float* attw_b  = (const float*)d_in[12];
    const float* out_W   = (const float*)d_in[13];
    const float* out_b   = (const float*)d_in[14];
    float* out = (float*)d_out;

    // ws layout (bytes):
    //   [0,        16711680)  vproj f16 [32640][256]
    //   [16711680, 32071680)  qkcat bf16 [10000][768] (slots in cols 512..768)
    //   [32071680, 32727040)  value_Wt | out_Wt | qk_Wt  bf16
    char* ws = (char*)d_ws;
    ushort_t* vproj    = (ushort_t*)ws;
    ushort_t* qkcat    = (ushort_t*)(ws + 16711680);
    ushort_t* value_Wt = (ushort_t*)(ws + 32071680);
    ushort_t* out_Wt   = (ushort_t*)(ws + 32071680 + 131072);
    ushort_t* qk_Wt    = (ushort_t*)(ws + 32071680 + 262144);

    // 1. weight transpose+convert -> Wt[n][k] bf16
    prep_w<<<dim3(8, 16, 4), 256, 0, stream>>>(
        value_W, out_W, off_W, attw_W, value_Wt, out_Wt, qk_Wt);
    // 2. fused value-proj (f16 out) + offset/attw-proj (bf16 out)
    gemm_vqk<<<984, 256, 0, stream>>>(value, value_Wt, value_b, vproj,
                                      query, qk_Wt, off_b, attw_b, qkcat);
    // 3. deformable sampling + softmax + camera mask/count -> slots in qkcat
    sample_k<<<dim3(10000, 2), 128, 0, stream>>>(qkcat, refp, vox, vproj);
    // 4. output projection + residual, f32 out
    gemm_out_k<<<dim3(79, 2), 256, 0, stream>>>(qkcat + 512, out_Wt, out_b,
                                                query, out);
}